// Round 7
// baseline (15995.308 us; speedup 1.0000x reference)
//
#include <hip/hip_runtime.h>
#include <cmath>

#define SS 512
#define BB 32
#define EE 128
#define HH 256
#define VV 10000
#define NROWS (SS*BB)   // 16384
#define VPAD 10048

typedef unsigned short ushort_t;
typedef __attribute__((ext_vector_type(8))) short bf16x8;
typedef __attribute__((ext_vector_type(4))) float f32x4;

#define MFMA(a,b,c) __builtin_amdgcn_mfma_f32_16x16x32_bf16((a),(b),(c),0,0,0)

__device__ __forceinline__ ushort_t f2bf(float x) {
    unsigned u = __float_as_uint(x);
    u = (u + 0x7FFFu + ((u >> 16) & 1u)) >> 16;   // RNE
    return (ushort_t)u;
}
__device__ __forceinline__ float bf2f(ushort_t h) {
    return __uint_as_float(((unsigned)h) << 16);
}
__device__ __forceinline__ float sigf(float x) { return 1.0f / (1.0f + __expf(-x)); }
__device__ __forceinline__ float tanhf_(float x) { return 1.0f - 2.0f / (__expf(2.0f * x) + 1.0f); }

// ---------------- zgemm: layer-1 x-part (b0 folded), bf16 PRE-SWIZZLED (R6-validated) ----
// Zsw[t][slot512][cellg64]: slot = w*64+q*16+n16, cellg = ((ug2*2+m)*4+r)*4+g.
__global__ __launch_bounds__(256)
void zgemm_sw(const float* __restrict__ Wk, const float* __restrict__ bias,
              const float* __restrict__ xin, const int* __restrict__ idx,
              ushort_t* __restrict__ Zsw)
{
    __shared__ float A[16][256];
    const int tid = threadIdx.x;
    const int m0 = blockIdx.x * 16;
    for (int i = tid; i < 16 * EE; i += 256) {
        const int r = i >> 7, cc = i & (EE - 1);
        const int m = m0 + r;
        const int t = m >> 5, b = m & (BB - 1);
        const int id = idx[b * SS + t];
        A[r][cc] = xin[(size_t)id * EE + cc];
    }
    __syncthreads();
    const float4 b4 = ((const float4*)bias)[tid];
    float4 acc[16];
#pragma unroll
    for (int i = 0; i < 16; i++) acc[i] = b4;
    for (int r = 0; r < EE; r++) {
        const float4 w = ((const float4*)(Wk + (size_t)r * 1024))[tid];
#pragma unroll
        for (int i = 0; i < 16; i++) {
            const float a = A[i][r];
            acc[i].x += a * w.x; acc[i].y += a * w.y;
            acc[i].z += a * w.z; acc[i].w += a * w.w;
        }
    }
    const int t = m0 >> 5, b0 = m0 & 31;
#pragma unroll
    for (int i = 0; i < 16; i++) {
        const int b = b0 + i;
        const float v4[4] = {acc[i].x, acc[i].y, acc[i].z, acc[i].w};
#pragma unroll
        for (int jj = 0; jj < 4; jj++) {
            const int col = 4 * tid + jj;
            const int g = col >> 8, u = col & 255;
            const int w = u >> 5, ug2 = (u >> 4) & 1, n16 = u & 15;
            const int slot = w * 64 + ((b >> 2) & 3) * 16 + n16;
            const int cell = ((ug2 * 2 + (b >> 4)) * 4) + (b & 3);
            Zsw[((size_t)t * 512 + slot) * 64 + cell * 4 + g] = f2bf(v4[jj]);
        }
    }
}

// ---------------- fp32[256 x 1024] -> bf16 [1024][256] transpose (R6-validated) --------
__global__ __launch_bounds__(256)
void wtgen(const float* __restrict__ src, ushort_t* __restrict__ dst)
{
    __shared__ float tile[64][65];
    const int tid = threadIdx.x;
    const int n0 = blockIdx.x * 64, k0 = blockIdx.y * 64;
    for (int i = tid; i < 4096; i += 256) {
        const int kk = i >> 6, nn = i & 63;
        tile[kk][nn] = src[(size_t)(k0 + kk) * 1024 + n0 + nn];
    }
    __syncthreads();
    for (int i = tid; i < 4096; i += 256) {
        const int nn = i >> 6, kk = i & 63;
        dst[(size_t)(n0 + nn) * 256 + k0 + kk] = f2bf(tile[kk][nn]);
    }
}

// ---------------- out_W -> bf16 transpose + padded bias (R3-validated) ----------------
__global__ __launch_bounds__(256)
void wtrans_kernel(const float* __restrict__ W, ushort_t* __restrict__ Wt)
{
    __shared__ float tile[64][65];
    const int tid = threadIdx.x;
    const int n0 = blockIdx.x * 64, k0 = blockIdx.y * 64;
    for (int i = tid; i < 4096; i += 256) {
        const int kk = i >> 6, nn = i & 63;
        const int n = n0 + nn;
        tile[kk][nn] = (n < VV) ? W[(size_t)(k0 + kk) * VV + n] : 0.f;
    }
    __syncthreads();
    for (int i = tid; i < 4096; i += 256) {
        const int nn = i >> 6, kk = i & 63;
        Wt[(size_t)(n0 + nn) * 256 + k0 + kk] = f2bf(tile[kk][nn]);
    }
}

__global__ __launch_bounds__(256)
void obset_kernel(const float* __restrict__ ob, float* __restrict__ obp)
{
    const int v = blockIdx.x * 256 + threadIdx.x;
    if (v < VPAD) obp[v] = (v < VV) ? ob[v] : -INFINITY;
}

// ---------------- single-block LSTM recurrence, no cross-block sync ----------------
// 512 thr = 8 waves, wave w owns cols [w*32, w*32+32). Slices (gate,col-half):
// VGPR: g0..g2/colA. LDS (loaded once): g3/colA, g0/colB. Streamed from L2: g1..3/colB.
// h lives in LDS (single buffer, 2 barriers/step); c-state in registers.
__global__ __launch_bounds__(512, 2)
void lstm_rec(const ushort_t* __restrict__ Wh, const ushort_t* __restrict__ zsw,
              const int* __restrict__ lens, ushort_t* __restrict__ outp)
{
    __shared__ ushort_t hA[32 * 264];          // 16.9 KB
    __shared__ ushort_t wsl[8 * 2 * 8 * 512];  // 128 KB, [w][s][kb][lane*8]
    const int tid = threadIdx.x;
    const int w = tid >> 6, lane = tid & 63;
    const int q = lane >> 4, n16 = lane & 15;
    const int colA = w * 32 + n16, colB = colA + 16;

    bf16x8 Bv[3][8];
#pragma unroll
    for (int g = 0; g < 3; g++)
#pragma unroll
        for (int kb = 0; kb < 8; kb++)
            Bv[g][kb] = *(const bf16x8*)&Wh[(size_t)(g * 256 + colA) * 256 + kb * 32 + q * 8];
    {
        const int n0 = 3 * 256 + colA, n1 = 0 * 256 + colB;
#pragma unroll
        for (int kb = 0; kb < 8; kb++) {
            *(bf16x8*)&wsl[((w * 2 + 0) * 8 + kb) * 512 + lane * 8] =
                *(const bf16x8*)&Wh[(size_t)n0 * 256 + kb * 32 + q * 8];
            *(bf16x8*)&wsl[((w * 2 + 1) * 8 + kb) * 512 + lane * 8] =
                *(const bf16x8*)&Wh[(size_t)n1 * 256 + kb * 32 + q * 8];
        }
    }
    const int nS1 = 1 * 256 + colB, nS2 = 2 * 256 + colB, nS3 = 3 * 256 + colB;

    int len2[2][4];
#pragma unroll
    for (int m = 0; m < 2; m++)
#pragma unroll
        for (int r = 0; r < 4; r++) len2[m][r] = lens[m * 16 + q * 4 + r];
    float cst[16];
#pragma unroll
    for (int i = 0; i < 16; i++) cst[i] = 0.f;
    __syncthreads();

    for (int t = 0; t < SS; t++) {
        const ushort_t* zp = zsw + ((size_t)t * 512 + tid) * 64;   // 128 B/lane contiguous
        bf16x8 z8[8];
#pragma unroll
        for (int i = 0; i < 8; i++) z8[i] = *(const bf16x8*)(zp + i * 8);

        f32x4 C[8][2];
#pragma unroll
        for (int s = 0; s < 8; s++)
#pragma unroll
            for (int m = 0; m < 2; m++) C[s][m] = (f32x4){0.f, 0.f, 0.f, 0.f};

        if (t > 0) {
#pragma unroll
            for (int kb = 0; kb < 8; kb++) {
                const bf16x8 A0 = *(const bf16x8*)&hA[n16 * 264 + kb * 32 + q * 8];
                const bf16x8 A1 = *(const bf16x8*)&hA[(16 + n16) * 264 + kb * 32 + q * 8];
                const bf16x8 L3 = *(const bf16x8*)&wsl[((w * 2 + 0) * 8 + kb) * 512 + lane * 8];
                const bf16x8 L4 = *(const bf16x8*)&wsl[((w * 2 + 1) * 8 + kb) * 512 + lane * 8];
                const bf16x8 S5 = *(const bf16x8*)&Wh[(size_t)nS1 * 256 + kb * 32 + q * 8];
                const bf16x8 S6 = *(const bf16x8*)&Wh[(size_t)nS2 * 256 + kb * 32 + q * 8];
                const bf16x8 S7 = *(const bf16x8*)&Wh[(size_t)nS3 * 256 + kb * 32 + q * 8];
                C[0][0] = MFMA(A0, Bv[0][kb], C[0][0]); C[0][1] = MFMA(A1, Bv[0][kb], C[0][1]);
                C[1][0] = MFMA(A0, Bv[1][kb], C[1][0]); C[1][1] = MFMA(A1, Bv[1][kb], C[1][1]);
                C[2][0] = MFMA(A0, Bv[2][kb], C[2][0]); C[2][1] = MFMA(A1, Bv[2][kb], C[2][1]);
                C[3][0] = MFMA(A0, L3, C[3][0]);        C[3][1] = MFMA(A1, L3, C[3][1]);
                C[4][0] = MFMA(A0, L4, C[4][0]);        C[4][1] = MFMA(A1, L4, C[4][1]);
                C[5][0] = MFMA(A0, S5, C[5][0]);        C[5][1] = MFMA(A1, S5, C[5][1]);
                C[6][0] = MFMA(A0, S6, C[6][0]);        C[6][1] = MFMA(A1, S6, C[6][1]);
                C[7][0] = MFMA(A0, S7, C[7][0]);        C[7][1] = MFMA(A1, S7, C[7][1]);
            }
        }
        __syncthreads();                       // hA(t-1) reads complete
#pragma unroll
        for (int ug2 = 0; ug2 < 2; ug2++)
#pragma unroll
        for (int m = 0; m < 2; m++)
#pragma unroll
        for (int r = 0; r < 4; r++) {
            const int cell = (ug2 * 2 + m) * 4 + r;
            const float zi = bf2f((ushort_t)z8[(cell * 4 + 0) >> 3][(cell * 4 + 0) & 7]) + C[ug2 ? 4 : 0][m][r];
            const float zg = bf2f((ushort_t)z8[(cell * 4 + 1) >> 3][(cell * 4 + 1) & 7]) + C[ug2 ? 5 : 1][m][r];
            const float zf = bf2f((ushort_t)z8[(cell * 4 + 2) >> 3][(cell * 4 + 2) & 7]) + C[ug2 ? 6 : 2][m][r];
            const float zo = bf2f((ushort_t)z8[(cell * 4 + 3) >> 3][(cell * 4 + 3) & 7]) + C[ug2 ? 7 : 3][m][r];
            const float cn = sigf(zf + 1.0f) * cst[cell] + sigf(zi) * tanhf_(zg);
            const float hn = sigf(zo) * tanhf_(cn);
            const bool act = (t < len2[m][r]);
            cst[cell] = act ? cn : cst[cell];
            const int col = w * 32 + ug2 * 16 + n16;
            const int b = m * 16 + q * 4 + r;
            const ushort_t hb = f2bf(hn);
            if (act) hA[b * 264 + col] = hb;   // inactive: old h persists
            outp[(size_t)t * 8192 + b * 256 + col] = act ? hb : (ushort_t)0;
        }
        __syncthreads();                       // hA(t) visible for next step
    }
}

// ---------------- layer-2 x-part GEMM + b1, output pre-swizzled (R6-validated) --------
__global__ __launch_bounds__(512, 2)
void xgemm2(const ushort_t* __restrict__ out1, const ushort_t* __restrict__ W2x,
            const float* __restrict__ b1v, ushort_t* __restrict__ Xsw)
{
    const int tid = threadIdx.x;
    const int w = tid >> 6, lane = tid & 63;
    const int q = lane >> 4, n16 = lane & 15;
    const int m0 = blockIdx.x * 128;           // 4 timesteps x 32 batch
#pragma unroll 1
    for (int i = 0; i < 8; i++) {
        const int n = (w * 8 + i) * 16 + n16;
        bf16x8 Bfr[8];
#pragma unroll
        for (int kb = 0; kb < 8; kb++)
            Bfr[kb] = *(const bf16x8*)&W2x[(size_t)n * 256 + kb * 32 + q * 8];
        const float bval = b1v[n];
        f32x4 Cc[8];
#pragma unroll
        for (int mt = 0; mt < 8; mt++) {
            Cc[mt] = (f32x4){0.f, 0.f, 0.f, 0.f};
            bf16x8 Af[8];
#pragma unroll
            for (int kb = 0; kb < 8; kb++)
                Af[kb] = *(const bf16x8*)&out1[(size_t)(m0 + mt * 16 + n16) * 256 + kb * 32 + q * 8];
#pragma unroll
            for (int kb = 0; kb < 8; kb++)
                Cc[mt] = MFMA(Af[kb], Bfr[kb], Cc[mt]);
        }
        const int g = n >> 8, u = n & 255;
        const int wT = u >> 5, ug2 = (u >> 4) & 1;
#pragma unroll
        for (int mt = 0; mt < 8; mt++)
#pragma unroll
            for (int r = 0; r < 4; r++) {
                const int row = m0 + mt * 16 + q * 4 + r;
                const int tt = row >> 5, b = row & 31;
                const int slot = wT * 64 + ((b >> 2) & 3) * 16 + n16;
                const int cell = ((ug2 * 2 + (b >> 4)) * 4) + (b & 3);
                Xsw[((size_t)tt * 512 + slot) * 64 + cell * 4 + g] = f2bf(Cc[mt][r] + bval);
            }
    }
}

// ---------------- MFMA bf16 fused projection + CE (R3-validated) ----------------
__global__ __launch_bounds__(256, 1)
void ce_kernel(const ushort_t* __restrict__ h2bf, const ushort_t* __restrict__ Wt,
               const float* __restrict__ obp, const int* __restrict__ y,
               const int* __restrict__ lens, float* __restrict__ out)
{
    __shared__ ushort_t h2t[64 * 264];
    __shared__ float lsw[4][64];
    __shared__ float tgt64[64];
    const int tid = threadIdx.x;
    const int w = tid >> 6, lane = tid & 63;
    const int q = lane >> 4, n16 = lane & 15;
    const int m0 = blockIdx.x * 64;

    for (int i = tid; i < 64 * 32; i += 256) {
        const int r = i >> 5, s = i & 31;
        *(uint4*)&h2t[r * 264 + s * 8] = *(const uint4*)(h2bf + (size_t)(m0 + r) * 256 + s * 8);
    }
    if (tid < 64) tgt64[tid] = 0.f;
    __syncthreads();

    bf16x8 A[4][8];
#pragma unroll
    for (int mt = 0; mt < 4; mt++) {
        const int row = mt * 16 + n16;
#pragma unroll
        for (int kb = 0; kb < 8; kb++)
            A[mt][kb] = *(const bf16x8*)&h2t[row * 264 + kb * 32 + q * 8];
    }
    int yv[16];
#pragma unroll
    for (int mt = 0; mt < 4; mt++)
#pragma unroll
        for (int r = 0; r < 4; r++) {
            const int m = m0 + mt * 16 + q * 4 + r;
            yv[mt * 4 + r] = y[(m & 31) * SS + (m >> 5)];
        }
    float lsum[16];
#pragma unroll
    for (int i = 0; i < 16; i++) lsum[i] = 0.f;

    const int cbase = w * 2512;
    for (int tile = 0; tile < 157; tile++) {
        const int n = cbase + tile * 16 + n16;
        const ushort_t* bp = Wt + (size_t)n * 256 + q * 8;
        bf16x8 B[8];
#pragma unroll
        for (int kb = 0; kb < 8; kb++) B[kb] = *(const bf16x8*)(bp + kb * 32);
        const float obv = obp[n];
        f32x4 C[4];
#pragma unroll
        for (int mt = 0; mt < 4; mt++) {
            C[mt] = (f32x4){0.f, 0.f, 0.f, 0.f};
#pragma unroll
            for (int kb = 0; kb < 8; kb++)
                C[mt] = MFMA(A[mt][kb], B[kb], C[mt]);
        }
#pragma unroll
        for (int mt = 0; mt < 4; mt++)
#pragma unroll
            for (int r = 0; r < 4; r++) {
                const float sc = C[mt][r] + obv;
                if (n == yv[mt * 4 + r]) tgt64[mt * 16 + q * 4 + r] = sc;
                lsum[mt * 4 + r] += __expf(sc - 16.0f);
            }
    }
#pragma unroll
    for (int i = 0; i < 16; i++) {
        float v = lsum[i];
        v += __shfl_xor(v, 1, 16); v += __shfl_xor(v, 2, 16);
        v += __shfl_xor(v, 4, 16); v += __shfl_xor(v, 8, 16);
        lsum[i] = v;
    }
    if (n16 == 0)
#pragma unroll
        for (int i = 0; i < 16; i++)
            lsw[w][(i >> 2) * 16 + q * 4 + (i & 3)] = lsum[i];
    __syncthreads();

    if (tid < 64) {
        const float l = lsw[0][tid] + lsw[1][tid] + lsw[2][tid] + lsw[3][tid];
        const float lse = 16.0f + __logf(l);
        const int m = m0 + tid;
        const int tt = m >> 5, bb = m & 31;
        const int yvv = y[bb * SS + tt];
        float local = (yvv != 0) ? (lse - tgt64[tid]) / (32.0f * (float)lens[bb]) : 0.f;
        for (int off = 1; off < 64; off <<= 1) local += __shfl_xor(local, off, 64);
        if (tid == 0) atomicAdd(out, local);
    }
}

extern "C" void kernel_launch(void* const* d_in, const int* in_sizes, int n_in,
                              void* d_out, int out_size, void* d_ws, size_t ws_size,
                              hipStream_t stream)
{
    const int*   input_x = (const int*)  d_in[0];
    const int*   input_y = (const int*)  d_in[1];
    const int*   lens    = (const int*)  d_in[2];
    const float* emb_W   = (const float*)d_in[3];
    const float* k0      = (const float*)d_in[4];
    const float* b0      = (const float*)d_in[5];
    const float* k1      = (const float*)d_in[6];
    const float* b1      = (const float*)d_in[7];
    const float* out_W   = (const float*)d_in[8];
    const float* out_b   = (const float*)d_in[9];
    float* out = (float*)d_out;

    char* p = (char*)d_ws;
    ushort_t* Zsw  = (ushort_t*)p;  p += (size_t)SS * 512 * 64 * 2;   // 33.55 MB
    ushort_t* Xsw  = (ushort_t*)p;  p += (size_t)SS * 512 * 64 * 2;   // 33.55 MB
    ushort_t* out1 = (ushort_t*)p;  p += (size_t)NROWS * 256 * 2;     // 8.39 MB
    ushort_t* h2bf = (ushort_t*)p;  p += (size_t)NROWS * 256 * 2;     // 8.39 MB
    ushort_t* W1h  = (ushort_t*)p;  p += (size_t)1024 * 256 * 2;
    ushort_t* W2h  = (ushort_t*)p;  p += (size_t)1024 * 256 * 2;
    ushort_t* W2x  = (ushort_t*)p;  p += (size_t)1024 * 256 * 2;
    ushort_t* Wt   = (ushort_t*)p;  p += (size_t)VPAD * 256 * 2;      // 5.14 MB
    float*    obp  = (float*)p;     p += (size_t)VPAD * 4;

    hipMemsetAsync(d_out, 0, sizeof(float), stream);

    zgemm_sw<<<NROWS / 16, 256, 0, stream>>>(k0, b0, emb_W, input_x, Zsw);
    wtgen<<<dim3(16, 4), 256, 0, stream>>>(k0 + (size_t)EE * 1024, W1h);
    wtgen<<<dim3(16, 4), 256, 0, stream>>>(k1 + (size_t)HH * 1024, W2h);
    wtgen<<<dim3(16, 4), 256, 0, stream>>>(k1, W2x);
    wtrans_kernel<<<dim3(VPAD / 64, 4), 256, 0, stream>>>(out_W, Wt);
    obset_kernel<<<(VPAD + 255) / 256, 256, 0, stream>>>(out_b, obp);

    lstm_rec<<<1, 512, 0, stream>>>(W1h, Zsw, lens, out1);
    xgemm2<<<128, 512, 0, stream>>>(out1, W2x, b1, Xsw);
    lstm_rec<<<1, 512, 0, stream>>>(W2h, Xsw, lens, h2bf);
    ce_kernel<<<NROWS / 64, 256, 0, stream>>>(h2bf, Wt, obp, input_y, lens, out);
}

// Round 8
// 11638.984 us; speedup vs baseline: 1.3743x; 1.3743x over previous
//
#include <hip/hip_runtime.h>
#include <hip/hip_fp8.h>
#include <cmath>

#define SS 512
#define BB 32
#define EE 128
#define HH 256
#define VV 10000
#define NROWS (SS*BB)   // 16384
#define VPAD 10048

typedef unsigned short ushort_t;
typedef unsigned char uchar_t;
typedef __attribute__((ext_vector_type(8))) short bf16x8;
typedef __attribute__((ext_vector_type(4))) float f32x4;

#define MFMA(a,b,c)  __builtin_amdgcn_mfma_f32_16x16x32_bf16((a),(b),(c),0,0,0)
#define MFMA8(a,b,c) __builtin_amdgcn_mfma_f32_16x16x32_fp8_fp8((a),(b),(c),0,0,0)

__device__ __forceinline__ ushort_t f2bf(float x) {
    unsigned u = __float_as_uint(x);
    u = (u + 0x7FFFu + ((u >> 16) & 1u)) >> 16;   // RNE
    return (ushort_t)u;
}
__device__ __forceinline__ float bf2f(ushort_t h) {
    return __uint_as_float(((unsigned)h) << 16);
}
__device__ __forceinline__ uchar_t f2fp8(float x) {
    __hip_fp8_e4m3 t(x);                           // OCP e4m3, HW convert on gfx950
    return (uchar_t)t.__x;
}
__device__ __forceinline__ float sigf(float x) { return 1.0f / (1.0f + __expf(-x)); }
__device__ __forceinline__ float tanhf_(float x) { return 1.0f - 2.0f / (__expf(2.0f * x) + 1.0f); }

// ---------------- zgemm: layer-1 x-part (b0 folded), bf16 PRE-SWIZZLED (R6/R7-validated) ----
__global__ __launch_bounds__(256)
void zgemm_sw(const float* __restrict__ Wk, const float* __restrict__ bias,
              const float* __restrict__ xin, const int* __restrict__ idx,
              ushort_t* __restrict__ Zsw)
{
    __shared__ float A[16][256];
    const int tid = threadIdx.x;
    const int m0 = blockIdx.x * 16;
    for (int i = tid; i < 16 * EE; i += 256) {
        const int r = i >> 7, cc = i & (EE - 1);
        const int m = m0 + r;
        const int t = m >> 5, b = m & (BB - 1);
        const int id = idx[b * SS + t];
        A[r][cc] = xin[(size_t)id * EE + cc];
    }
    __syncthreads();
    const float4 b4 = ((const float4*)bias)[tid];
    float4 acc[16];
#pragma unroll
    for (int i = 0; i < 16; i++) acc[i] = b4;
    for (int r = 0; r < EE; r++) {
        const float4 w = ((const float4*)(Wk + (size_t)r * 1024))[tid];
#pragma unroll
        for (int i = 0; i < 16; i++) {
            const float a = A[i][r];
            acc[i].x += a * w.x; acc[i].y += a * w.y;
            acc[i].z += a * w.z; acc[i].w += a * w.w;
        }
    }
    const int t = m0 >> 5, b0 = m0 & 31;
#pragma unroll
    for (int i = 0; i < 16; i++) {
        const int b = b0 + i;
        const float v4[4] = {acc[i].x, acc[i].y, acc[i].z, acc[i].w};
#pragma unroll
        for (int jj = 0; jj < 4; jj++) {
            const int col = 4 * tid + jj;
            const int g = col >> 8, u = col & 255;
            const int w = u >> 5, ug2 = (u >> 4) & 1, n16 = u & 15;
            const int slot = w * 64 + ((b >> 2) & 3) * 16 + n16;
            const int cell = ((ug2 * 2 + (b >> 4)) * 4) + (b & 3);
            Zsw[((size_t)t * 512 + slot) * 64 + cell * 4 + g] = f2bf(v4[jj]);
        }
    }
}

// ---------------- fp32[256 x 1024] -> bf16 [1024][256] transpose (R6-validated) --------
__global__ __launch_bounds__(256)
void wtgen(const float* __restrict__ src, ushort_t* __restrict__ dst)
{
    __shared__ float tile[64][65];
    const int tid = threadIdx.x;
    const int n0 = blockIdx.x * 64, k0 = blockIdx.y * 64;
    for (int i = tid; i < 4096; i += 256) {
        const int kk = i >> 6, nn = i & 63;
        tile[kk][nn] = src[(size_t)(k0 + kk) * 1024 + n0 + nn];
    }
    __syncthreads();
    for (int i = tid; i < 4096; i += 256) {
        const int nn = i >> 6, kk = i & 63;
        dst[(size_t)(n0 + nn) * 256 + k0 + kk] = f2bf(tile[kk][nn]);
    }
}

// ---------------- fp32[256 x 1024] -> fp8 e4m3 [1024][256] transpose ----------------
__global__ __launch_bounds__(256)
void wf8gen(const float* __restrict__ src, uchar_t* __restrict__ dst)
{
    __shared__ float tile[64][65];
    const int tid = threadIdx.x;
    const int n0 = blockIdx.x * 64, k0 = blockIdx.y * 64;
    for (int i = tid; i < 4096; i += 256) {
        const int kk = i >> 6, nn = i & 63;
        tile[kk][nn] = src[(size_t)(k0 + kk) * 1024 + n0 + nn];
    }
    __syncthreads();
    for (int i = tid; i < 4096; i += 256) {
        const int nn = i >> 6, kk = i & 63;
        dst[(size_t)(n0 + nn) * 256 + k0 + kk] = f2fp8(tile[kk][nn]);
    }
}

// ---------------- out_W -> bf16 transpose + padded bias (R3-validated) ----------------
__global__ __launch_bounds__(256)
void wtrans_kernel(const float* __restrict__ W, ushort_t* __restrict__ Wt)
{
    __shared__ float tile[64][65];
    const int tid = threadIdx.x;
    const int n0 = blockIdx.x * 64, k0 = blockIdx.y * 64;
    for (int i = tid; i < 4096; i += 256) {
        const int kk = i >> 6, nn = i & 63;
        const int n = n0 + nn;
        tile[kk][nn] = (n < VV) ? W[(size_t)(k0 + kk) * VV + n] : 0.f;
    }
    __syncthreads();
    for (int i = tid; i < 4096; i += 256) {
        const int nn = i >> 6, kk = i & 63;
        Wt[(size_t)(n0 + nn) * 256 + k0 + kk] = f2bf(tile[kk][nn]);
    }
}

__global__ __launch_bounds__(256)
void obset_kernel(const float* __restrict__ ob, float* __restrict__ obp)
{
    const int v = blockIdx.x * 256 + threadIdx.x;
    if (v < VPAD) obp[v] = (v < VV) ? ob[v] : -INFINITY;
}

// ---------------- single-block fp8 LSTM recurrence ----------------
// 8 waves; wave w owns units u in [w*32, w*32+32). 8 output tiles/wave = (gate g, ug2).
// Residency: g0 -> VGPR (Bv, 32 regs), g1/g2 -> LDS Bl (128 KB, fragment-major),
// g3 -> streamed from L2 each step (64 KB/block/step). h in LDS as fp8,
// A-fragment-major. z (x-part+bias) pre-swizzled bf16, streamed.
__global__ __launch_bounds__(512)
void lstm_rec8(const uchar_t* __restrict__ Wf8, const ushort_t* __restrict__ zsw,
               const int* __restrict__ lens, ushort_t* __restrict__ outp)
{
    __shared__ uchar_t Bl[131072];     // [(w*4+ti)*8+kb][lane][8]
    __shared__ uchar_t hA8[8192];      // [m][kb][lane][8]  (A-frag major)
    const int tid = threadIdx.x;
    const int w = tid >> 6, lane = tid & 63;
    const int q = lane >> 4, n16 = lane & 15;

    // stage g1,g2 (cols 256..767) into LDS, fragment-major
    for (int idx = tid; idx < 16384; idx += 512) {
        const int lane_ = idx & 63, kb = (idx >> 6) & 7, ti = (idx >> 9) & 3, ww = idx >> 11;
        const int g = 1 + (ti >> 1), ug2 = ti & 1;
        const int col = g * 256 + ww * 32 + ug2 * 16 + (lane_ & 15);
        *(unsigned long*)&Bl[(size_t)idx * 8] =
            *(const unsigned long*)&Wf8[(size_t)col * 256 + kb * 32 + (lane_ >> 4) * 8];
    }
    for (int i = tid; i < 8192 / 8; i += 512) ((unsigned long*)hA8)[i] = 0ul;

    long Bv[2][8];                     // g0, both ug2 halves
#pragma unroll
    for (int ug2 = 0; ug2 < 2; ug2++)
#pragma unroll
        for (int kb = 0; kb < 8; kb++)
            Bv[ug2][kb] = *(const long*)&Wf8[(size_t)(w * 32 + ug2 * 16 + n16) * 256 + kb * 32 + q * 8];
    const int c3 = 3 * 256 + w * 32 + n16;

    int len2[2][4];
#pragma unroll
    for (int m = 0; m < 2; m++)
#pragma unroll
        for (int r = 0; r < 4; r++) len2[m][r] = lens[m * 16 + q * 4 + r];
    float cst[16];
#pragma unroll
    for (int i = 0; i < 16; i++) cst[i] = 0.f;
    __syncthreads();

    for (int t = 0; t < SS; t++) {
        const ushort_t* zp = zsw + ((size_t)t * 512 + tid) * 64;   // 128 B/lane contiguous
        bf16x8 z8[8];
#pragma unroll
        for (int i = 0; i < 8; i++) z8[i] = *(const bf16x8*)(zp + i * 8);
        long G3[2][8];                 // g3, streamed (prefetched for whole step)
#pragma unroll
        for (int ug2 = 0; ug2 < 2; ug2++)
#pragma unroll
            for (int kb = 0; kb < 8; kb++)
                G3[ug2][kb] = *(const long*)&Wf8[(size_t)(c3 + ug2 * 16) * 256 + kb * 32 + q * 8];

        f32x4 C[4][2][2];
#pragma unroll
        for (int g = 0; g < 4; g++)
#pragma unroll
            for (int ug2 = 0; ug2 < 2; ug2++)
#pragma unroll
                for (int m = 0; m < 2; m++) C[g][ug2][m] = (f32x4){0.f, 0.f, 0.f, 0.f};

        if (t > 0) {
#pragma unroll
            for (int kb = 0; kb < 8; kb++) {
                const long A0 = *(const long*)&hA8[((0 * 8 + kb) * 64 + lane) * 8];
                const long A1 = *(const long*)&hA8[((1 * 8 + kb) * 64 + lane) * 8];
                const long L0 = *(const long*)&Bl[(size_t)(((w * 4 + 0) * 8 + kb) * 64 + lane) * 8];
                const long L1 = *(const long*)&Bl[(size_t)(((w * 4 + 1) * 8 + kb) * 64 + lane) * 8];
                const long L2 = *(const long*)&Bl[(size_t)(((w * 4 + 2) * 8 + kb) * 64 + lane) * 8];
                const long L3 = *(const long*)&Bl[(size_t)(((w * 4 + 3) * 8 + kb) * 64 + lane) * 8];
                C[0][0][0] = MFMA8(A0, Bv[0][kb], C[0][0][0]);
                C[0][0][1] = MFMA8(A1, Bv[0][kb], C[0][0][1]);
                C[0][1][0] = MFMA8(A0, Bv[1][kb], C[0][1][0]);
                C[0][1][1] = MFMA8(A1, Bv[1][kb], C[0][1][1]);
                C[1][0][0] = MFMA8(A0, L0, C[1][0][0]);
                C[1][0][1] = MFMA8(A1, L0, C[1][0][1]);
                C[1][1][0] = MFMA8(A0, L1, C[1][1][0]);
                C[1][1][1] = MFMA8(A1, L1, C[1][1][1]);
                C[2][0][0] = MFMA8(A0, L2, C[2][0][0]);
                C[2][0][1] = MFMA8(A1, L2, C[2][0][1]);
                C[2][1][0] = MFMA8(A0, L3, C[2][1][0]);
                C[2][1][1] = MFMA8(A1, L3, C[2][1][1]);
                C[3][0][0] = MFMA8(A0, G3[0][kb], C[3][0][0]);
                C[3][0][1] = MFMA8(A1, G3[0][kb], C[3][0][1]);
                C[3][1][0] = MFMA8(A0, G3[1][kb], C[3][1][0]);
                C[3][1][1] = MFMA8(A1, G3[1][kb], C[3][1][1]);
            }
        }
        __syncthreads();               // hA8(t-1) reads complete
#pragma unroll
        for (int ug2 = 0; ug2 < 2; ug2++)
#pragma unroll
        for (int m = 0; m < 2; m++)
#pragma unroll
        for (int r = 0; r < 4; r++) {
            const int cell = (ug2 * 2 + m) * 4 + r;
            const int i4 = cell * 4;
            const float zi = bf2f((ushort_t)z8[(i4 + 0) >> 3][(i4 + 0) & 7]) + C[0][ug2][m][r];
            const float zg = bf2f((ushort_t)z8[(i4 + 1) >> 3][(i4 + 1) & 7]) + C[1][ug2][m][r];
            const float zf = bf2f((ushort_t)z8[(i4 + 2) >> 3][(i4 + 2) & 7]) + C[2][ug2][m][r];
            const float zo = bf2f((ushort_t)z8[(i4 + 3) >> 3][(i4 + 3) & 7]) + C[3][ug2][m][r];
            const float cn = sigf(zf + 1.0f) * cst[cell] + sigf(zi) * tanhf_(zg);
            const float hn = sigf(zo) * tanhf_(cn);
            const bool act = (t < len2[m][r]);
            cst[cell] = act ? cn : cst[cell];
            const int col = w * 32 + ug2 * 16 + n16;   // unit index u (k-dim next step)
            const int b = m * 16 + q * 4 + r;
            if (act)                  // writer->A-frag mapping: kb=w, qt=ug2*2+(n16>>3), row=b&15, j=n16&7
                hA8[((m * 8 + w) * 64 + (ug2 * 2 + (n16 >> 3)) * 16 + (q * 4 + r)) * 8 + (n16 & 7)] = f2fp8(hn);
            outp[(size_t)t * 8192 + b * 256 + col] = act ? f2bf(hn) : (ushort_t)0;
        }
        __syncthreads();               // hA8(t) visible for next step
    }
}

// ---------------- layer-2 x-part GEMM + b1, output pre-swizzled (R6/R7-validated) --------
__global__ __launch_bounds__(512, 2)
void xgemm2(const ushort_t* __restrict__ out1, const ushort_t* __restrict__ W2x,
            const float* __restrict__ b1v, ushort_t* __restrict__ Xsw)
{
    const int tid = threadIdx.x;
    const int w = tid >> 6, lane = tid & 63;
    const int q = lane >> 4, n16 = lane & 15;
    const int m0 = blockIdx.x * 128;           // 4 timesteps x 32 batch
#pragma unroll 1
    for (int i = 0; i < 8; i++) {
        const int n = (w * 8 + i) * 16 + n16;
        bf16x8 Bfr[8];
#pragma unroll
        for (int kb = 0; kb < 8; kb++)
            Bfr[kb] = *(const bf16x8*)&W2x[(size_t)n * 256 + kb * 32 + q * 8];
        const float bval = b1v[n];
        f32x4 Cc[8];
#pragma unroll
        for (int mt = 0; mt < 8; mt++) {
            Cc[mt] = (f32x4){0.f, 0.f, 0.f, 0.f};
            bf16x8 Af[8];
#pragma unroll
            for (int kb = 0; kb < 8; kb++)
                Af[kb] = *(const bf16x8*)&out1[(size_t)(m0 + mt * 16 + n16) * 256 + kb * 32 + q * 8];
#pragma unroll
            for (int kb = 0; kb < 8; kb++)
                Cc[mt] = MFMA(Af[kb], Bfr[kb], Cc[mt]);
        }
        const int g = n >> 8, u = n & 255;
        const int wT = u >> 5, ug2 = (u >> 4) & 1;
#pragma unroll
        for (int mt = 0; mt < 8; mt++)
#pragma unroll
            for (int r = 0; r < 4; r++) {
                const int row = m0 + mt * 16 + q * 4 + r;
                const int tt = row >> 5, b = row & 31;
                const int slot = wT * 64 + ((b >> 2) & 3) * 16 + n16;
                const int cell = ((ug2 * 2 + (b >> 4)) * 4) + (b & 3);
                Xsw[((size_t)tt * 512 + slot) * 64 + cell * 4 + g] = f2bf(Cc[mt][r] + bval);
            }
    }
}

// ---------------- MFMA bf16 fused projection + CE (R3-validated) ----------------
__global__ __launch_bounds__(256, 1)
void ce_kernel(const ushort_t* __restrict__ h2bf, const ushort_t* __restrict__ Wt,
               const float* __restrict__ obp, const int* __restrict__ y,
               const int* __restrict__ lens, float* __restrict__ out)
{
    __shared__ ushort_t h2t[64 * 264];
    __shared__ float lsw[4][64];
    __shared__ float tgt64[64];
    const int tid = threadIdx.x;
    const int w = tid >> 6, lane = tid & 63;
    const int q = lane >> 4, n16 = lane & 15;
    const int m0 = blockIdx.x * 64;

    for (int i = tid; i < 64 * 32; i += 256) {
        const int r = i >> 5, s = i & 31;
        *(uint4*)&h2t[r * 264 + s * 8] = *(const uint4*)(h2bf + (size_t)(m0 + r) * 256 + s * 8);
    }
    if (tid < 64) tgt64[tid] = 0.f;
    __syncthreads();

    bf16x8 A[4][8];
#pragma unroll
    for (int mt = 0; mt < 4; mt++) {
        const int row = mt * 16 + n16;
#pragma unroll
        for (int kb = 0; kb < 8; kb++)
            A[mt][kb] = *(const bf16x8*)&h2t[row * 264 + kb * 32 + q * 8];
    }
    int yv[16];
#pragma unroll
    for (int mt = 0; mt < 4; mt++)
#pragma unroll
        for (int r = 0; r < 4; r++) {
            const int m = m0 + mt * 16 + q * 4 + r;
            yv[mt * 4 + r] = y[(m & 31) * SS + (m >> 5)];
        }
    float lsum[16];
#pragma unroll
    for (int i = 0; i < 16; i++) lsum[i] = 0.f;

    const int cbase = w * 2512;
    for (int tile = 0; tile < 157; tile++) {
        const int n = cbase + tile * 16 + n16;
        const ushort_t* bp = Wt + (size_t)n * 256 + q * 8;
        bf16x8 B[8];
#pragma unroll
        for (int kb = 0; kb < 8; kb++) B[kb] = *(const bf16x8*)(bp + kb * 32);
        const float obv = obp[n];
        f32x4 C[4];
#pragma unroll
        for (int mt = 0; mt < 4; mt++) {
            C[mt] = (f32x4){0.f, 0.f, 0.f, 0.f};
#pragma unroll
            for (int kb = 0; kb < 8; kb++)
                C[mt] = MFMA(A[mt][kb], B[kb], C[mt]);
        }
#pragma unroll
        for (int mt = 0; mt < 4; mt++)
#pragma unroll
            for (int r = 0; r < 4; r++) {
                const float sc = C[mt][r] + obv;
                if (n == yv[mt * 4 + r]) tgt64[mt * 16 + q * 4 + r] = sc;
                lsum[mt * 4 + r] += __expf(sc - 16.0f);
            }
    }
#pragma unroll
    for (int i = 0; i < 16; i++) {
        float v = lsum[i];
        v += __shfl_xor(v, 1, 16); v += __shfl_xor(v, 2, 16);
        v += __shfl_xor(v, 4, 16); v += __shfl_xor(v, 8, 16);
        lsum[i] = v;
    }
    if (n16 == 0)
#pragma unroll
        for (int i = 0; i < 16; i++)
            lsw[w][(i >> 2) * 16 + q * 4 + (i & 3)] = lsum[i];
    __syncthreads();

    if (tid < 64) {
        const float l = lsw[0][tid] + lsw[1][tid] + lsw[2][tid] + lsw[3][tid];
        const float lse = 16.0f + __logf(l);
        const int m = m0 + tid;
        const int tt = m >> 5, bb = m & 31;
        const int yvv = y[bb * SS + tt];
        float local = (yvv != 0) ? (lse - tgt64[tid]) / (32.0f * (float)lens[bb]) : 0.f;
        for (int off = 1; off < 64; off <<= 1) local += __shfl_xor(local, off, 64);
        if (tid == 0) atomicAdd(out, local);
    }
}

extern "C" void kernel_launch(void* const* d_in, const int* in_sizes, int n_in,
                              void* d_out, int out_size, void* d_ws, size_t ws_size,
                              hipStream_t stream)
{
    const int*   input_x = (const int*)  d_in[0];
    const int*   input_y = (const int*)  d_in[1];
    const int*   lens    = (const int*)  d_in[2];
    const float* emb_W   = (const float*)d_in[3];
    const float* k0      = (const float*)d_in[4];
    const float* b0      = (const float*)d_in[5];
    const float* k1      = (const float*)d_in[6];
    const float* b1      = (const float*)d_in[7];
    const float* out_W   = (const float*)d_in[8];
    const float* out_b   = (const float*)d_in[9];
    float* out = (float*)d_out;

    char* p = (char*)d_ws;
    ushort_t* Zsw  = (ushort_t*)p;  p += (size_t)SS * 512 * 64 * 2;   // 33.55 MB
    ushort_t* Xsw  = (ushort_t*)p;  p += (size_t)SS * 512 * 64 * 2;   // 33.55 MB
    ushort_t* out1 = (ushort_t*)p;  p += (size_t)NROWS * 256 * 2;     // 8.39 MB
    ushort_t* h2bf = (ushort_t*)p;  p += (size_t)NROWS * 256 * 2;     // 8.39 MB
    uchar_t*  Wf81 = (uchar_t*)p;   p += (size_t)1024 * 256;          // 256 KB
    uchar_t*  Wf82 = (uchar_t*)p;   p += (size_t)1024 * 256;          // 256 KB
    ushort_t* W2x  = (ushort_t*)p;  p += (size_t)1024 * 256 * 2;      // 512 KB
    ushort_t* Wt   = (ushort_t*)p;  p += (size_t)VPAD * 256 * 2;      // 5.14 MB
    float*    obp  = (float*)p;     p += (size_t)VPAD * 4;

    hipMemsetAsync(d_out, 0, sizeof(float), stream);

    zgemm_sw<<<NROWS / 16, 256, 0, stream>>>(k0, b0, emb_W, input_x, Zsw);
    wf8gen<<<dim3(16, 4), 256, 0, stream>>>(k0 + (size_t)EE * 1024, Wf81);  // L1 h-part fp8
    wf8gen<<<dim3(16, 4), 256, 0, stream>>>(k1 + (size_t)HH * 1024, Wf82);  // L2 h-part fp8
    wtgen<<<dim3(16, 4), 256, 0, stream>>>(k1, W2x);                        // L2 x-part bf16
    wtrans_kernel<<<dim3(VPAD / 64, 4), 256, 0, stream>>>(out_W, Wt);
    obset_kernel<<<(VPAD + 255) / 256, 256, 0, stream>>>(out_b, obp);

    lstm_rec8<<<1, 512, 0, stream>>>(Wf81, Zsw, lens, out1);
    xgemm2<<<128, 512, 0, stream>>>(out1, W2x, b1, Xsw);
    lstm_rec8<<<1, 512, 0, stream>>>(Wf82, Xsw, lens, h2bf);
    ce_kernel<<<NROWS / 64, 256, 0, stream>>>(h2bf, Wt, obp, input_y, lens, out);
}

// Round 9
// 3236.072 us; speedup vs baseline: 4.9428x; 3.5966x over previous
//
#include <hip/hip_runtime.h>
#include <hip/hip_fp8.h>
#include <cmath>

#define SS 512
#define BB 32
#define EE 128
#define HH 256
#define VV 10000
#define NROWS (SS*BB)   // 16384
#define VPAD 10048

typedef unsigned short ushort_t;
typedef unsigned char uchar_t;
typedef __attribute__((ext_vector_type(8))) short bf16x8;
typedef __attribute__((ext_vector_type(4))) float f32x4;

#define MFMA(a,b,c)  __builtin_amdgcn_mfma_f32_16x16x32_bf16((a),(b),(c),0,0,0)
#define MFMA8(a,b,c) __builtin_amdgcn_mfma_f32_16x16x32_fp8_fp8((a),(b),(c),0,0,0)

__device__ __forceinline__ ushort_t f2bf(float x) {
    unsigned u = __float_as_uint(x);
    u = (u + 0x7FFFu + ((u >> 16) & 1u)) >> 16;   // RNE
    return (ushort_t)u;
}
__device__ __forceinline__ float bf2f(ushort_t h) {
    return __uint_as_float(((unsigned)h) << 16);
}
__device__ __forceinline__ uchar_t f2fp8(float x) {
    __hip_fp8_e4m3 t(x);                           // OCP e4m3
    return (uchar_t)t.__x;
}
__device__ __forceinline__ float sigf(float x) { return 1.0f / (1.0f + __expf(-x)); }
__device__ __forceinline__ float tanhf_(float x) { return 1.0f - 2.0f / (__expf(2.0f * x) + 1.0f); }

// ---------------- zgemm: layer-1 x-part (b0 folded), plain bf16 [row][1024] ----------
// (R1-validated fp32 GEMM core, bf16 packed stores)
__global__ __launch_bounds__(256)
void zgemm_b(const float* __restrict__ Wk, const float* __restrict__ bias,
             const float* __restrict__ xin, const int* __restrict__ idx,
             ushort_t* __restrict__ Zb)
{
    __shared__ float A[16][256];
    const int tid = threadIdx.x;
    const int m0 = blockIdx.x * 16;
    for (int i = tid; i < 16 * EE; i += 256) {
        const int r = i >> 7, cc = i & (EE - 1);
        const int m = m0 + r;
        const int t = m >> 5, b = m & (BB - 1);
        const int id = idx[b * SS + t];
        A[r][cc] = xin[(size_t)id * EE + cc];
    }
    __syncthreads();
    const float4 b4 = ((const float4*)bias)[tid];
    float4 acc[16];
#pragma unroll
    for (int i = 0; i < 16; i++) acc[i] = b4;
    for (int r = 0; r < EE; r++) {
        const float4 w = ((const float4*)(Wk + (size_t)r * 1024))[tid];
#pragma unroll
        for (int i = 0; i < 16; i++) {
            const float a = A[i][r];
            acc[i].x += a * w.x; acc[i].y += a * w.y;
            acc[i].z += a * w.z; acc[i].w += a * w.w;
        }
    }
#pragma unroll
    for (int i = 0; i < 16; i++) {
        ushort_t o4[4] = { f2bf(acc[i].x), f2bf(acc[i].y), f2bf(acc[i].z), f2bf(acc[i].w) };
        *(uint2*)&Zb[(size_t)(m0 + i) * 1024 + 4 * tid] = *(uint2*)o4;
    }
}

// ---------------- h-part weights -> fp8 fragment-major --------------------------------
// dst[((nt*8+kb)*64 + lane)*8 + j] = fp8(src[(kb*32 + (lane>>4)*8 + j)*1024 + nt*16 + (lane&15)])
__global__ __launch_bounds__(512)
void wf8sw(const float* __restrict__ src, uchar_t* __restrict__ dst)
{
    const int nt = blockIdx.x;
    const int kb = threadIdx.x >> 6, lane = threadIdx.x & 63;
    const int q = lane >> 4, n16 = lane & 15;
    uchar_t v[8];
#pragma unroll
    for (int j = 0; j < 8; j++)
        v[j] = f2fp8(src[(size_t)(kb * 32 + q * 8 + j) * 1024 + nt * 16 + n16]);
    *(unsigned long long*)&dst[((size_t)(nt * 8 + kb) * 64 + lane) * 8] = *(unsigned long long*)v;
}

// ---------------- fp32[256 x 1024] -> bf16 [1024][256] transpose (R6-validated) --------
__global__ __launch_bounds__(256)
void wtgen(const float* __restrict__ src, ushort_t* __restrict__ dst)
{
    __shared__ float tile[64][65];
    const int tid = threadIdx.x;
    const int n0 = blockIdx.x * 64, k0 = blockIdx.y * 64;
    for (int i = tid; i < 4096; i += 256) {
        const int kk = i >> 6, nn = i & 63;
        tile[kk][nn] = src[(size_t)(k0 + kk) * 1024 + n0 + nn];
    }
    __syncthreads();
    for (int i = tid; i < 4096; i += 256) {
        const int nn = i >> 6, kk = i & 63;
        dst[(size_t)(n0 + nn) * 256 + k0 + kk] = f2bf(tile[kk][nn]);
    }
}

// ---------------- out_W -> bf16 transpose + padded bias (R3-validated) ----------------
__global__ __launch_bounds__(256)
void wtrans_kernel(const float* __restrict__ W, ushort_t* __restrict__ Wt)
{
    __shared__ float tile[64][65];
    const int tid = threadIdx.x;
    const int n0 = blockIdx.x * 64, k0 = blockIdx.y * 64;
    for (int i = tid; i < 4096; i += 256) {
        const int kk = i >> 6, nn = i & 63;
        const int n = n0 + nn;
        tile[kk][nn] = (n < VV) ? W[(size_t)(k0 + kk) * VV + n] : 0.f;
    }
    __syncthreads();
    for (int i = tid; i < 4096; i += 256) {
        const int nn = i >> 6, kk = i & 63;
        Wt[(size_t)(n0 + nn) * 256 + k0 + kk] = f2bf(tile[kk][nn]);
    }
}

__global__ __launch_bounds__(256)
void obset_kernel(const float* __restrict__ ob, float* __restrict__ obp)
{
    const int v = blockIdx.x * 256 + threadIdx.x;
    if (v < VPAD) obp[v] = (v < VV) ? ob[v] : -INFINITY;
}

// ---------------- batch-parallel LSTM recurrence: 1 block per batch element ----------
// 512 thr = 8 waves. h broadcast into all 16 A-rows (all C rows identical).
// Wave w owns n-tiles w*8..w*8+7 (cols w*128..+128). Waves 0-3: LDS-resident
// weights (gates i,g = 128 KB, staged once). Waves 4-7: streamed from L2.
// Gate math on threads 0-255 (unit = tid); c in registers; h fp8 double-buffered LDS.
// t >= len is block-uniform -> zero-fill remaining rows and exit.
__global__ __launch_bounds__(512)
void lstm_b32(const uchar_t* __restrict__ Wsw, const ushort_t* __restrict__ zin,
              const int* __restrict__ lens, ushort_t* __restrict__ outp)
{
    __shared__ uchar_t Bl[131072];     // nt 0..31, fragment-major
    __shared__ float zbuf[1024];
    __shared__ uchar_t h8[2][256];
    const int tid = threadIdx.x;
    const int w = tid >> 6, lane = tid & 63;
    const int q = lane >> 4, n16 = lane & 15;
    const int b = blockIdx.x;
    const int len = lens[b];

    for (int i = tid; i < 131072 / 16; i += 512)
        *(uint4*)&Bl[i * 16] = *(const uint4*)&Wsw[i * 16];
    if (tid < 256) { h8[0][tid] = 0; h8[1][tid] = 0; }
    float c = 0.f;
    __syncthreads();

    for (int t = 0; t < SS; t++) {
        if (t >= len) {                // uniform: freeze + zero outputs, done
            uint4 zz; zz.x = zz.y = zz.z = zz.w = 0u;
            const int nseg = (SS - t) * 32;
            for (int i = tid; i < nseg; i += 512) {
                const int tt = t + (i >> 5), seg = i & 31;
                *(uint4*)&outp[((size_t)tt * 32 + b) * 256 + seg * 8] = zz;
            }
            break;
        }
        const size_t row = (size_t)t * 32 + b;
        ushort_t z4[4] = {0, 0, 0, 0};
        if (tid < 256) {               // x-part preact (bias folded), issued early
#pragma unroll
            for (int g = 0; g < 4; g++) z4[g] = zin[row * 1024 + g * 256 + tid];
        }
        const int rd = t & 1, wr = rd ^ 1;
        unsigned long long Af[8];
#pragma unroll
        for (int kb = 0; kb < 8; kb++)
            Af[kb] = *(const unsigned long long*)&h8[rd][kb * 32 + q * 8];  // LDS broadcast

        f32x4 C[8];
#pragma unroll
        for (int i = 0; i < 8; i++) C[i] = (f32x4){0.f, 0.f, 0.f, 0.f};
        if (w < 4) {
#pragma unroll
            for (int kb = 0; kb < 8; kb++)
#pragma unroll
                for (int i = 0; i < 8; i++) {
                    const unsigned long long Bf =
                        *(const unsigned long long*)&Bl[(((w * 8 + i) * 8 + kb) * 64 + lane) * 8];
                    C[i] = MFMA8((long)Af[kb], (long)Bf, C[i]);
                }
        } else {
#pragma unroll
            for (int kb = 0; kb < 8; kb++)
#pragma unroll
                for (int i = 0; i < 8; i++) {
                    const unsigned long long Bf =
                        *(const unsigned long long*)&Wsw[((size_t)((w * 8 + i) * 8 + kb) * 64 + lane) * 8];
                    C[i] = MFMA8((long)Af[kb], (long)Bf, C[i]);
                }
        }
        if (q == 0) {                  // all C rows identical; row 0 via q=0 lanes
#pragma unroll
            for (int i = 0; i < 8; i++) zbuf[(w * 8 + i) * 16 + n16] = C[i][0];
        }
        __syncthreads();               // zbuf ready; h8[rd] reads done
        if (tid < 256) {
            const float zi = bf2f(z4[0]) + zbuf[tid];
            const float zg = bf2f(z4[1]) + zbuf[256 + tid];
            const float zf = bf2f(z4[2]) + zbuf[512 + tid];
            const float zo = bf2f(z4[3]) + zbuf[768 + tid];
            const float cn = sigf(zf + 1.0f) * c + sigf(zi) * tanhf_(zg);
            const float hn = sigf(zo) * tanhf_(cn);
            c = cn;
            h8[wr][tid] = f2fp8(hn);
            outp[row * 256 + tid] = f2bf(hn);
        }
        __syncthreads();               // h8[wr] visible for next step
    }
}

// ---------------- layer-2 x-part GEMM + b1, plain bf16 [row][1024] out ----------------
// (R6-validated GEMM core; plain-layout store)
__global__ __launch_bounds__(512, 2)
void xgemm2p(const ushort_t* __restrict__ out1, const ushort_t* __restrict__ W2x,
             const float* __restrict__ b1v, ushort_t* __restrict__ Xp)
{
    const int tid = threadIdx.x;
    const int w = tid >> 6, lane = tid & 63;
    const int q = lane >> 4, n16 = lane & 15;
    const int m0 = blockIdx.x * 128;           // 4 timesteps x 32 batch
#pragma unroll 1
    for (int i = 0; i < 8; i++) {
        const int n = (w * 8 + i) * 16 + n16;
        bf16x8 Bfr[8];
#pragma unroll
        for (int kb = 0; kb < 8; kb++)
            Bfr[kb] = *(const bf16x8*)&W2x[(size_t)n * 256 + kb * 32 + q * 8];
        const float bval = b1v[n];
        f32x4 Cc[8];
#pragma unroll
        for (int mt = 0; mt < 8; mt++) {
            Cc[mt] = (f32x4){0.f, 0.f, 0.f, 0.f};
            bf16x8 Af[8];
#pragma unroll
            for (int kb = 0; kb < 8; kb++)
                Af[kb] = *(const bf16x8*)&out1[(size_t)(m0 + mt * 16 + n16) * 256 + kb * 32 + q * 8];
#pragma unroll
            for (int kb = 0; kb < 8; kb++)
                Cc[mt] = MFMA(Af[kb], Bfr[kb], Cc[mt]);
        }
#pragma unroll
        for (int mt = 0; mt < 8; mt++)
#pragma unroll
            for (int r = 0; r < 4; r++) {
                const int rrow = m0 + mt * 16 + q * 4 + r;
                Xp[(size_t)rrow * 1024 + n] = f2bf(Cc[mt][r] + bval);
            }
    }
}

// ---------------- MFMA bf16 fused projection + CE (R3-validated) ----------------
__global__ __launch_bounds__(256, 1)
void ce_kernel(const ushort_t* __restrict__ h2bf, const ushort_t* __restrict__ Wt,
               const float* __restrict__ obp, const int* __restrict__ y,
               const int* __restrict__ lens, float* __restrict__ out)
{
    __shared__ ushort_t h2t[64 * 264];
    __shared__ float lsw[4][64];
    __shared__ float tgt64[64];
    const int tid = threadIdx.x;
    const int w = tid >> 6, lane = tid & 63;
    const int q = lane >> 4, n16 = lane & 15;
    const int m0 = blockIdx.x * 64;

    for (int i = tid; i < 64 * 32; i += 256) {
        const int r = i >> 5, s = i & 31;
        *(uint4*)&h2t[r * 264 + s * 8] = *(const uint4*)(h2bf + (size_t)(m0 + r) * 256 + s * 8);
    }
    if (tid < 64) tgt64[tid] = 0.f;
    __syncthreads();

    bf16x8 A[4][8];
#pragma unroll
    for (int mt = 0; mt < 4; mt++) {
        const int row = mt * 16 + n16;
#pragma unroll
        for (int kb = 0; kb < 8; kb++)
            A[mt][kb] = *(const bf16x8*)&h2t[row * 264 + kb * 32 + q * 8];
    }
    int yv[16];
#pragma unroll
    for (int mt = 0; mt < 4; mt++)
#pragma unroll
        for (int r = 0; r < 4; r++) {
            const int m = m0 + mt * 16 + q * 4 + r;
            yv[mt * 4 + r] = y[(m & 31) * SS + (m >> 5)];
        }
    float lsum[16];
#pragma unroll
    for (int i = 0; i < 16; i++) lsum[i] = 0.f;

    const int cbase = w * 2512;
    for (int tile = 0; tile < 157; tile++) {
        const int n = cbase + tile * 16 + n16;
        const ushort_t* bp = Wt + (size_t)n * 256 + q * 8;
        bf16x8 B[8];
#pragma unroll
        for (int kb = 0; kb < 8; kb++) B[kb] = *(const bf16x8*)(bp + kb * 32);
        const float obv = obp[n];
        f32x4 C[4];
#pragma unroll
        for (int mt = 0; mt < 4; mt++) {
            C[mt] = (f32x4){0.f, 0.f, 0.f, 0.f};
#pragma unroll
            for (int kb = 0; kb < 8; kb++)
                C[mt] = MFMA(A[mt][kb], B[kb], C[mt]);
        }
#pragma unroll
        for (int mt = 0; mt < 4; mt++)
#pragma unroll
            for (int r = 0; r < 4; r++) {
                const float sc = C[mt][r] + obv;
                if (n == yv[mt * 4 + r]) tgt64[mt * 16 + q * 4 + r] = sc;
                lsum[mt * 4 + r] += __expf(sc - 16.0f);
            }
    }
#pragma unroll
    for (int i = 0; i < 16; i++) {
        float v = lsum[i];
        v += __shfl_xor(v, 1, 16); v += __shfl_xor(v, 2, 16);
        v += __shfl_xor(v, 4, 16); v += __shfl_xor(v, 8, 16);
        lsum[i] = v;
    }
    if (n16 == 0)
#pragma unroll
        for (int i = 0; i < 16; i++)
            lsw[w][(i >> 2) * 16 + q * 4 + (i & 3)] = lsum[i];
    __syncthreads();

    if (tid < 64) {
        const float l = lsw[0][tid] + lsw[1][tid] + lsw[2][tid] + lsw[3][tid];
        const float lse = 16.0f + __logf(l);
        const int m = m0 + tid;
        const int tt = m >> 5, bb = m & 31;
        const int yvv = y[bb * SS + tt];
        float local = (yvv != 0) ? (lse - tgt64[tid]) / (32.0f * (float)lens[bb]) : 0.f;
        for (int off = 1; off < 64; off <<= 1) local += __shfl_xor(local, off, 64);
        if (tid == 0) atomicAdd(out, local);
    }
}

extern "C" void kernel_launch(void* const* d_in, const int* in_sizes, int n_in,
                              void* d_out, int out_size, void* d_ws, size_t ws_size,
                              hipStream_t stream)
{
    const int*   input_x = (const int*)  d_in[0];
    const int*   input_y = (const int*)  d_in[1];
    const int*   lens    = (const int*)  d_in[2];
    const float* emb_W   = (const float*)d_in[3];
    const float* k0      = (const float*)d_in[4];
    const float* b0      = (const float*)d_in[5];
    const float* k1      = (const float*)d_in[6];
    const float* b1      = (const float*)d_in[7];
    const float* out_W   = (const float*)d_in[8];
    const float* out_b   = (const float*)d_in[9];
    float* out = (float*)d_out;

    char* p = (char*)d_ws;
    ushort_t* Zb   = (ushort_t*)p;  p += (size_t)NROWS * 1024 * 2;    // 33.55 MB
    ushort_t* Xp   = (ushort_t*)p;  p += (size_t)NROWS * 1024 * 2;    // 33.55 MB
    ushort_t* out1 = (ushort_t*)p;  p += (size_t)NROWS * 256 * 2;     // 8.39 MB
    ushort_t* h2bf = (ushort_t*)p;  p += (size_t)NROWS * 256 * 2;     // 8.39 MB
    uchar_t*  Wsw1 = (uchar_t*)p;   p += (size_t)1024 * 256;          // 256 KB
    uchar_t*  Wsw2 = (uchar_t*)p;   p += (size_t)1024 * 256;          // 256 KB
    ushort_t* W2x  = (ushort_t*)p;  p += (size_t)1024 * 256 * 2;      // 512 KB
    ushort_t* Wt   = (ushort_t*)p;  p += (size_t)VPAD * 256 * 2;      // 5.14 MB
    float*    obp  = (float*)p;     p += (size_t)VPAD * 4;

    hipMemsetAsync(d_out, 0, sizeof(float), stream);

    zgemm_b<<<NROWS / 16, 256, 0, stream>>>(k0, b0, emb_W, input_x, Zb);
    wf8sw<<<64, 512, 0, stream>>>(k0 + (size_t)EE * 1024, Wsw1);   // L1 h-part fp8 frag-major
    wf8sw<<<64, 512, 0, stream>>>(k1 + (size_t)HH * 1024, Wsw2);   // L2 h-part fp8 frag-major
    wtgen<<<dim3(16, 4), 256, 0, stream>>>(k1, W2x);               // L2 x-part bf16
    wtrans_kernel<<<dim3(VPAD / 64, 4), 256, 0, stream>>>(out_W, Wt);
    obset_kernel<<<(VPAD + 255) / 256, 256, 0, stream>>>(out_b, obp);

    lstm_b32<<<BB, 512, 0, stream>>>(Wsw1, Zb, lens, out1);
    xgemm2p<<<128, 512, 0, stream>>>(out1, W2x, b1, Xp);
    lstm_b32<<<BB, 512, 0, stream>>>(Wsw2, Xp, lens, h2bf);
    ce_kernel<<<NROWS / 64, 256, 0, stream>>>(h2bf, Wt, obp, input_y, lens, out);
}

// Round 10
// 2386.867 us; speedup vs baseline: 6.7014x; 1.3558x over previous
//
#include <hip/hip_runtime.h>
#include <hip/hip_fp8.h>
#include <cmath>

#define SS 512
#define BB 32
#define EE 128
#define HH 256
#define VV 10000
#define NROWS (SS*BB)   // 16384
#define VPAD 10048

typedef unsigned short ushort_t;
typedef unsigned char uchar_t;
typedef __attribute__((ext_vector_type(8))) short bf16x8;
typedef __attribute__((ext_vector_type(4))) float f32x4;

#define MFMA(a,b,c)  __builtin_amdgcn_mfma_f32_16x16x32_bf16((a),(b),(c),0,0,0)
#define MFMA8(a,b,c) __builtin_amdgcn_mfma_f32_16x16x32_fp8_fp8((a),(b),(c),0,0,0)

__device__ __forceinline__ ushort_t f2bf(float x) {
    unsigned u = __float_as_uint(x);
    u = (u + 0x7FFFu + ((u >> 16) & 1u)) >> 16;   // RNE
    return (ushort_t)u;
}
__device__ __forceinline__ float bf2f(ushort_t h) {
    return __uint_as_float(((unsigned)h) << 16);
}
__device__ __forceinline__ uchar_t f2fp8(float x) {
    __hip_fp8_e4m3 t(x);                           // OCP e4m3
    return (uchar_t)t.__x;
}
__device__ __forceinline__ float sigf(float x) { return 1.0f / (1.0f + __expf(-x)); }
__device__ __forceinline__ float tanhf_(float x) { return 1.0f - 2.0f / (__expf(2.0f * x) + 1.0f); }

// ---------------- zgemm: layer-1 x-part (b0 folded), plain bf16 [row][1024] (R9-validated) ----
__global__ __launch_bounds__(256)
void zgemm_b(const float* __restrict__ Wk, const float* __restrict__ bias,
             const float* __restrict__ xin, const int* __restrict__ idx,
             ushort_t* __restrict__ Zb)
{
    __shared__ float A[16][256];
    const int tid = threadIdx.x;
    const int m0 = blockIdx.x * 16;
    for (int i = tid; i < 16 * EE; i += 256) {
        const int r = i >> 7, cc = i & (EE - 1);
        const int m = m0 + r;
        const int t = m >> 5, b = m & (BB - 1);
        const int id = idx[b * SS + t];
        A[r][cc] = xin[(size_t)id * EE + cc];
    }
    __syncthreads();
    const float4 b4 = ((const float4*)bias)[tid];
    float4 acc[16];
#pragma unroll
    for (int i = 0; i < 16; i++) acc[i] = b4;
    for (int r = 0; r < EE; r++) {
        const float4 w = ((const float4*)(Wk + (size_t)r * 1024))[tid];
#pragma unroll
        for (int i = 0; i < 16; i++) {
            const float a = A[i][r];
            acc[i].x += a * w.x; acc[i].y += a * w.y;
            acc[i].z += a * w.z; acc[i].w += a * w.w;
        }
    }
#pragma unroll
    for (int i = 0; i < 16; i++) {
        ushort_t o4[4] = { f2bf(acc[i].x), f2bf(acc[i].y), f2bf(acc[i].z), f2bf(acc[i].w) };
        *(uint2*)&Zb[(size_t)(m0 + i) * 1024 + 4 * tid] = *(uint2*)o4;
    }
}

// ---------------- h-part weights -> fp8 fragment-major (R9-validated) ------------------
__global__ __launch_bounds__(512)
void wf8sw(const float* __restrict__ src, uchar_t* __restrict__ dst)
{
    const int nt = blockIdx.x;
    const int kb = threadIdx.x >> 6, lane = threadIdx.x & 63;
    const int q = lane >> 4, n16 = lane & 15;
    uchar_t v[8];
#pragma unroll
    for (int j = 0; j < 8; j++)
        v[j] = f2fp8(src[(size_t)(kb * 32 + q * 8 + j) * 1024 + nt * 16 + n16]);
    *(unsigned long long*)&dst[((size_t)(nt * 8 + kb) * 64 + lane) * 8] = *(unsigned long long*)v;
}

// ---------------- fp32[256 x 1024] -> bf16 [1024][256] transpose (R6-validated) --------
__global__ __launch_bounds__(256)
void wtgen(const float* __restrict__ src, ushort_t* __restrict__ dst)
{
    __shared__ float tile[64][65];
    const int tid = threadIdx.x;
    const int n0 = blockIdx.x * 64, k0 = blockIdx.y * 64;
    for (int i = tid; i < 4096; i += 256) {
        const int kk = i >> 6, nn = i & 63;
        tile[kk][nn] = src[(size_t)(k0 + kk) * 1024 + n0 + nn];
    }
    __syncthreads();
    for (int i = tid; i < 4096; i += 256) {
        const int nn = i >> 6, kk = i & 63;
        dst[(size_t)(n0 + nn) * 256 + k0 + kk] = f2bf(tile[kk][nn]);
    }
}

// ---------------- out_W -> bf16 transpose + padded bias (R3-validated) ----------------
__global__ __launch_bounds__(256)
void wtrans_kernel(const float* __restrict__ W, ushort_t* __restrict__ Wt)
{
    __shared__ float tile[64][65];
    const int tid = threadIdx.x;
    const int n0 = blockIdx.x * 64, k0 = blockIdx.y * 64;
    for (int i = tid; i < 4096; i += 256) {
        const int kk = i >> 6, nn = i & 63;
        const int n = n0 + nn;
        tile[kk][nn] = (n < VV) ? W[(size_t)(k0 + kk) * VV + n] : 0.f;
    }
    __syncthreads();
    for (int i = tid; i < 4096; i += 256) {
        const int nn = i >> 6, kk = i & 63;
        Wt[(size_t)(n0 + nn) * 256 + k0 + kk] = f2bf(tile[kk][nn]);
    }
}

__global__ __launch_bounds__(256)
void obset_kernel(const float* __restrict__ ob, float* __restrict__ obp)
{
    const int v = blockIdx.x * 256 + threadIdx.x;
    if (v < VPAD) obp[v] = (v < VV) ? ob[v] : -INFINITY;
}

// ---------------- batch-parallel LSTM, ALL weights resident (VGPR+LDS) ----------------
// 1 block per batch element; 256 thr = 4 waves (1/SIMD, __launch_bounds__(256,1) ->
// VGPR cap 512). Wave w owns n-tiles w*16..w*16+15: tiles 0..6 in VGPRs (112 regs),
// tiles 7..15 in LDS (4 waves x 9 x 4 KB = 144 KB, staged once). Zero per-step global
// weight traffic. h broadcast into all 16 A-rows; h fp8 double-buffered in LDS.
// t >= len is block-uniform -> zero-fill rest and exit (R9-validated).
__global__ __launch_bounds__(256, 1)
void lstm_b32r(const uchar_t* __restrict__ Wsw, const ushort_t* __restrict__ zin,
               const int* __restrict__ lens, ushort_t* __restrict__ outp)
{
    __shared__ uchar_t Bl[147456];     // 36 tiles: [(w*9+j)*8+kb][lane][8]
    __shared__ float zbuf[1024];
    __shared__ uchar_t h8[2][256];
    const int tid = threadIdx.x;
    const int w = tid >> 6, lane = tid & 63;
    const int q = lane >> 4, n16 = lane & 15;
    const int b = blockIdx.x;
    const int len = lens[b];

    // stage LDS tiles (i = 7..15 of each wave) : dst qword d = ((w*9+j)*8+kb)*64+lane
    for (int u = tid; u < 9216; u += 256) {
        const int d = u * 2;
        const int lane2 = d & 63, kb = (d >> 6) & 7, wj = d >> 9;
        const int ww = wj / 9, j = wj - ww * 9;
        const size_t s = (((size_t)(ww * 16 + 7 + j) * 8 + kb) * 64 + lane2) * 8;
        *(uint4*)&Bl[(size_t)d * 8] = *(const uint4*)&Wsw[s];
    }
    // VGPR tiles i = 0..6
    unsigned long long Bv[7][8];
#pragma unroll
    for (int i = 0; i < 7; i++)
#pragma unroll
        for (int kb = 0; kb < 8; kb++)
            Bv[i][kb] = *(const unsigned long long*)
                &Wsw[((size_t)((w * 16 + i) * 8 + kb) * 64 + lane) * 8];
    h8[0][tid] = 0; h8[1][tid] = 0;
    float c = 0.f;
    __syncthreads();

    for (int t = 0; t < SS; t++) {
        if (t >= len) {                // uniform: zero remaining rows, done
            uint4 zz; zz.x = zz.y = zz.z = zz.w = 0u;
            const int nseg = (SS - t) * 32;
            for (int i = tid; i < nseg; i += 256) {
                const int tt = t + (i >> 5), seg = i & 31;
                *(uint4*)&outp[((size_t)tt * 32 + b) * 256 + seg * 8] = zz;
            }
            break;
        }
        const size_t row = (size_t)t * 32 + b;
        ushort_t z4[4];
#pragma unroll
        for (int g = 0; g < 4; g++) z4[g] = zin[row * 1024 + g * 256 + tid];

        const int rd = t & 1, wr = rd ^ 1;
        unsigned long long Af[8];
#pragma unroll
        for (int kb = 0; kb < 8; kb++)
            Af[kb] = *(const unsigned long long*)&h8[rd][kb * 32 + q * 8];  // LDS broadcast

        f32x4 C[16];
#pragma unroll
        for (int i = 0; i < 16; i++) C[i] = (f32x4){0.f, 0.f, 0.f, 0.f};
#pragma unroll
        for (int kb = 0; kb < 8; kb++) {
#pragma unroll
            for (int i = 0; i < 7; i++)
                C[i] = MFMA8((long)Af[kb], (long)Bv[i][kb], C[i]);
#pragma unroll
            for (int i = 7; i < 16; i++) {
                const unsigned long long Bf = *(const unsigned long long*)
                    &Bl[(((size_t)(w * 9 + (i - 7)) * 8 + kb) * 64 + lane) * 8];
                C[i] = MFMA8((long)Af[kb], (long)Bf, C[i]);
            }
        }
        if (q == 0) {                  // all C rows identical; take row 0 via q=0 lanes
#pragma unroll
            for (int i = 0; i < 16; i++) zbuf[(w * 16 + i) * 16 + n16] = C[i][0];
        }
        __syncthreads();               // zbuf ready; h8[rd] reads done
        {
            const float zi = bf2f(z4[0]) + zbuf[tid];
            const float zg = bf2f(z4[1]) + zbuf[256 + tid];
            const float zf = bf2f(z4[2]) + zbuf[512 + tid];
            const float zo = bf2f(z4[3]) + zbuf[768 + tid];
            const float cn = sigf(zf + 1.0f) * c + sigf(zi) * tanhf_(zg);
            const float hn = sigf(zo) * tanhf_(cn);
            c = cn;
            h8[wr][tid] = f2fp8(hn);
            outp[row * 256 + tid] = f2bf(hn);
        }
        __syncthreads();               // h8[wr] visible for next step
    }
}

// ---------------- layer-2 x-part GEMM + b1, plain bf16 out (R9-validated) ----------------
__global__ __launch_bounds__(512, 2)
void xgemm2p(const ushort_t* __restrict__ out1, const ushort_t* __restrict__ W2x,
             const float* __restrict__ b1v, ushort_t* __restrict__ Xp)
{
    const int tid = threadIdx.x;
    const int w = tid >> 6, lane = tid & 63;
    const int q = lane >> 4, n16 = lane & 15;
    const int m0 = blockIdx.x * 128;           // 4 timesteps x 32 batch
#pragma unroll 1
    for (int i = 0; i < 8; i++) {
        const int n = (w * 8 + i) * 16 + n16;
        bf16x8 Bfr[8];
#pragma unroll
        for (int kb = 0; kb < 8; kb++)
            Bfr[kb] = *(const bf16x8*)&W2x[(size_t)n * 256 + kb * 32 + q * 8];
        const float bval = b1v[n];
        f32x4 Cc[8];
#pragma unroll
        for (int mt = 0; mt < 8; mt++) {
            Cc[mt] = (f32x4){0.f, 0.f, 0.f, 0.f};
            bf16x8 Af[8];
#pragma unroll
            for (int kb = 0; kb < 8; kb++)
                Af[kb] = *(const bf16x8*)&out1[(size_t)(m0 + mt * 16 + n16) * 256 + kb * 32 + q * 8];
#pragma unroll
            for (int kb = 0; kb < 8; kb++)
                Cc[mt] = MFMA(Af[kb], Bfr[kb], Cc[mt]);
        }
#pragma unroll
        for (int mt = 0; mt < 8; mt++)
#pragma unroll
            for (int r = 0; r < 4; r++) {
                const int rrow = m0 + mt * 16 + q * 4 + r;
                Xp[(size_t)rrow * 1024 + n] = f2bf(Cc[mt][r] + bval);
            }
    }
}

// ---------------- MFMA bf16 fused projection + CE (R3-validated) ----------------
__global__ __launch_bounds__(256, 1)
void ce_kernel(const ushort_t* __restrict__ h2bf, const ushort_t* __restrict__ Wt,
               const float* __restrict__ obp, const int* __restrict__ y,
               const int* __restrict__ lens, float* __restrict__ out)
{
    __shared__ ushort_t h2t[64 * 264];
    __shared__ float lsw[4][64];
    __shared__ float tgt64[64];
    const int tid = threadIdx.x;
    const int w = tid >> 6, lane = tid & 63;
    const int q = lane >> 4, n16 = lane & 15;
    const int m0 = blockIdx.x * 64;

    for (int i = tid; i < 64 * 32; i += 256) {
        const int r = i >> 5, s = i & 31;
        *(uint4*)&h2t[r * 264 + s * 8] = *(const uint4*)(h2bf + (size_t)(m0 + r) * 256 + s * 8);
    }
    if (tid < 64) tgt64[tid] = 0.f;
    __syncthreads();

    bf16x8 A[4][8];
#pragma unroll
    for (int mt = 0; mt < 4; mt++) {
        const int row = mt * 16 + n16;
#pragma unroll
        for (int kb = 0; kb < 8; kb++)
            A[mt][kb] = *(const bf16x8*)&h2t[row * 264 + kb * 32 + q * 8];
    }
    int yv[16];
#pragma unroll
    for (int mt = 0; mt < 4; mt++)
#pragma unroll
        for (int r = 0; r < 4; r++) {
            const int m = m0 + mt * 16 + q * 4 + r;
            yv[mt * 4 + r] = y[(m & 31) * SS + (m >> 5)];
        }
    float lsum[16];
#pragma unroll
    for (int i = 0; i < 16; i++) lsum[i] = 0.f;

    const int cbase = w * 2512;
    for (int tile = 0; tile < 157; tile++) {
        const int n = cbase + tile * 16 + n16;
        const ushort_t* bp = Wt + (size_t)n * 256 + q * 8;
        bf16x8 B[8];
#pragma unroll
        for (int kb = 0; kb < 8; kb++) B[kb] = *(const bf16x8*)(bp + kb * 32);
        const float obv = obp[n];
        f32x4 C[4];
#pragma unroll
        for (int mt = 0; mt < 4; mt++) {
            C[mt] = (f32x4){0.f, 0.f, 0.f, 0.f};
#pragma unroll
            for (int kb = 0; kb < 8; kb++)
                C[mt] = MFMA(A[mt][kb], B[kb], C[mt]);
        }
#pragma unroll
        for (int mt = 0; mt < 4; mt++)
#pragma unroll
            for (int r = 0; r < 4; r++) {
                const float sc = C[mt][r] + obv;
                if (n == yv[mt * 4 + r]) tgt64[mt * 16 + q * 4 + r] = sc;
                lsum[mt * 4 + r] += __expf(sc - 16.0f);
            }
    }
#pragma unroll
    for (int i = 0; i < 16; i++) {
        float v = lsum[i];
        v += __shfl_xor(v, 1, 16); v += __shfl_xor(v, 2, 16);
        v += __shfl_xor(v, 4, 16); v += __shfl_xor(v, 8, 16);
        lsum[i] = v;
    }
    if (n16 == 0)
#pragma unroll
        for (int i = 0; i < 16; i++)
            lsw[w][(i >> 2) * 16 + q * 4 + (i & 3)] = lsum[i];
    __syncthreads();

    if (tid < 64) {
        const float l = lsw[0][tid] + lsw[1][tid] + lsw[2][tid] + lsw[3][tid];
        const float lse = 16.0f + __logf(l);
        const int m = m0 + tid;
        const int tt = m >> 5, bb = m & 31;
        const int yvv = y[bb * SS + tt];
        float local = (yvv != 0) ? (lse - tgt64[tid]) / (32.0f * (float)lens[bb]) : 0.f;
        for (int off = 1; off < 64; off <<= 1) local += __shfl_xor(local, off, 64);
        if (tid == 0) atomicAdd(out, local);
    }
}

extern "C" void kernel_launch(void* const* d_in, const int* in_sizes, int n_in,
                              void* d_out, int out_size, void* d_ws, size_t ws_size,
                              hipStream_t stream)
{
    const int*   input_x = (const int*)  d_in[0];
    const int*   input_y = (const int*)  d_in[1];
    const int*   lens    = (const int*)  d_in[2];
    const float* emb_W   = (const float*)d_in[3];
    const float* k0      = (const float*)d_in[4];
    const float* b0      = (const float*)d_in[5];
    const float* k1      = (const float*)d_in[6];
    const float* b1      = (const float*)d_in[7];
    const float* out_W   = (const float*)d_in[8];
    const float* out_b   = (const float*)d_in[9];
    float* out = (float*)d_out;

    char* p = (char*)d_ws;
    ushort_t* Zb   = (ushort_t*)p;  p += (size_t)NROWS * 1024 * 2;    // 33.55 MB
    ushort_t* Xp   = (ushort_t*)p;  p += (size_t)NROWS * 1024 * 2;    // 33.55 MB
    ushort_t* out1 = (ushort_t*)p;  p += (size_t)NROWS * 256 * 2;     // 8.39 MB
    ushort_t* h2bf = (ushort_t*)p;  p += (size_t)NROWS * 256 * 2;     // 8.39 MB
    uchar_t*  Wsw1 = (uchar_t*)p;   p += (size_t)1024 * 256;          // 256 KB
    uchar_t*  Wsw2 = (uchar_t*)p;   p += (size_t)1024 * 256;          // 256 KB
    ushort_t* W2x  = (ushort_t*)p;  p += (size_t)1024 * 256 * 2;      // 512 KB
    ushort_t* Wt   = (ushort_t*)p;  p += (size_t)VPAD * 256 * 2;      // 5.14 MB
    float*    obp  = (float*)p;     p += (size_t)VPAD * 4;

    hipMemsetAsync(d_out, 0, sizeof(float), stream);

    zgemm_b<<<NROWS / 16, 256, 0, stream>>>(k0, b0, emb_W, input_x, Zb);
    wf8sw<<<64, 512, 0, stream>>>(k0 + (size_t)EE * 1024, Wsw1);   // L1 h-part fp8 frag-major
    wf8sw<<<64, 512, 0, stream>>>(k1 + (size_t)HH * 1024, Wsw2);   // L2 h-part fp8 frag-major
    wtgen<<<dim3(16, 4), 256, 0, stream>>>(k1, W2x);               // L2 x-part bf16
    wtrans_kernel<<<dim3(VPAD / 64, 4), 256, 0, stream>>>(out_W, Wt);
    obset_kernel<<<(VPAD + 255) / 256, 256, 0, stream>>>(out_b, obp);

    lstm_b32r<<<BB, 256, 0, stream>>>(Wsw1, Zb, lens, out1);
    xgemm2p<<<128, 512, 0, stream>>>(out1, W2x, b1, Xp);
    lstm_b32r<<<BB, 256, 0, stream>>>(Wsw2, Xp, lens, h2bf);
    ce_kernel<<<NROWS / 64, 256, 0, stream>>>(h2bf, Wt, obp, input_y, lens, out);
}